// Round 11
// baseline (117.392 us; speedup 1.0000x reference)
//
#include <hip/hip_runtime.h>

#define TSEQ 2304
#define DIN  1024
#define NH   8
#define DD   64
#define NC   1536
#define MROWS 4608
#define L2E  1.44269504f
#define EF   2.71828183f

typedef __attribute__((ext_vector_type(8))) short bf16x8;
typedef __attribute__((ext_vector_type(4))) float f32x4;
typedef __attribute__((ext_vector_type(4))) unsigned short u16x4;
typedef __attribute__((ext_vector_type(4))) unsigned int u32x4;

__device__ __forceinline__ unsigned short f2bf(float f){
    union { float f; unsigned int u; } x; x.f = f;
    unsigned int r = x.u + 0x7FFFu + ((x.u >> 16) & 1u);
    return (unsigned short)(r >> 16);
}

// raw v_exp_f32: D = 2^S0, no libm guard code (inputs bounded +-10 here)
__device__ __forceinline__ float exp2raw(float x){
    float r;
    asm("v_exp_f32 %0, %1" : "=v"(r) : "v"(x));
    return r;
}

// two f32 -> packed [bf16(b):bf16(a)] in one VALU op
__device__ __forceinline__ unsigned int cvtpk(float a, float b){
    unsigned int r;
    asm("v_cvt_pk_bf16_f32 %0, %1, %2" : "=v"(r) : "v"(a), "v"(b));
    return r;
}

__device__ __forceinline__ void gload_lds16(const void* g, void* l){
    __builtin_amdgcn_global_load_lds(
        (const __attribute__((address_space(1))) void*)g,
        (__attribute__((address_space(3))) void*)l, 16, 0, 0);
}

struct WArgs {
    const float* W[9];   // [seg*3+proj], seg0=s, seg1=m, seg2=e; proj0=q,1=k,2=v
    const float* g[3];
    const float* bv[3];
};

// Fused preprocessing: blocks [0,1152) build Wb, [1152,1224) bias, [1224,5832) LN
__global__ __launch_bounds__(256) void k_pre(WArgs a, const float* __restrict__ x,
                                             unsigned short* __restrict__ wb,
                                             float* __restrict__ bias,
                                             unsigned short* __restrict__ nrm)
{
    __shared__ float lds[64][65];
    __shared__ float red[4][64];
    __shared__ float r1[4], r2[4];
    const int bid = blockIdx.x;
    const int tid = threadIdx.x;
    if (bid < 1152){
        const int dt = bid & 15, h = (bid >> 4) & 7, sp = bid >> 7;
        const int seg = sp / 3, proj = sp % 3;
        const float* W = a.W[seg*3 + proj];
        const float* g = a.g[seg];
        const int d0 = dt * 64;
        {
            const int e = tid & 63, rq = tid >> 6;
#pragma unroll
            for (int rr = 0; rr < 16; ++rr){
                const int dl = rr*4 + rq;
                lds[dl][e] = W[((size_t)h*DIN + d0 + dl)*DD + e];
            }
        }
        __syncthreads();
        {
            const int dl = tid & 63, eq = tid >> 6;
            const int n0 = proj*512 + h*64;
            const float gv = g[h*DIN + d0 + dl];
#pragma unroll
            for (int rr = 0; rr < 16; ++rr){
                const int el = eq*16 + rr;
                wb[((size_t)seg*NC + n0 + el)*DIN + d0 + dl] = f2bf(lds[dl][el] * gv);
            }
        }
    } else if (bid < 1224){
        const int u = bid - 1152;
        const int h = u & 7, sp = u >> 3;
        const int seg = sp / 3, proj = sp % 3;
        const float* W  = a.W[seg*3 + proj];
        const float* bv = a.bv[seg];
        const int e = tid & 63, dc = tid >> 6;
        float sum = 0.f;
        for (int i = 0; i < 256; ++i){
            const int d = dc*256 + i;
            sum += bv[h*DIN + d] * W[((size_t)h*DIN + d)*DD + e];
        }
        red[dc][e] = sum;
        __syncthreads();
        if (dc == 0)
            bias[seg*NC + proj*512 + h*64 + e] = red[0][e] + red[1][e] + red[2][e] + red[3][e];
    } else {
        const int row = bid - 1224;
        const float* xr = x + (size_t)row * DIN;
        f32x4 v = *(const f32x4*)&xr[tid*4];
        float s1 = v[0]+v[1]+v[2]+v[3];
        float s2 = v[0]*v[0]+v[1]*v[1]+v[2]*v[2]+v[3]*v[3];
#pragma unroll
        for (int m = 1; m < 64; m <<= 1){ s1 += __shfl_xor(s1, m); s2 += __shfl_xor(s2, m); }
        const int wid = tid >> 6;
        if ((tid & 63) == 0){ r1[wid] = s1; r2[wid] = s2; }
        __syncthreads();
        s1 = r1[0]+r1[1]+r1[2]+r1[3];
        s2 = r2[0]+r2[1]+r2[2]+r2[3];
        const float mean = s1 * (1.f/1024.f);
        const float var  = s2 * (1.f/1024.f) - mean*mean;
        const float rstd = rsqrtf(var + 1e-5f);
        u16x4 ov;
#pragma unroll
        for (int j = 0; j < 4; ++j) ov[j] = f2bf((v[j]-mean)*rstd);
        *(u16x4*)&nrm[(size_t)row*DIN + tid*4] = ov;
    }
}

// C[4608][1536] = nrm @ Wb[seg]^T + bias; q,k scattered to [b][h][t][64];
// V written DIRECTLY TRANSPOSED to vt[b][h][e][t]. q pre-scaled by 0.125*log2e.
__global__ __launch_bounds__(256) void k_gemm(
    const unsigned short* __restrict__ A,
    const unsigned short* __restrict__ Wb,
    const float* __restrict__ bias,
    unsigned short* __restrict__ qo,
    unsigned short* __restrict__ ko,
    unsigned short* __restrict__ vt)
{
    __shared__ unsigned short As[128*32];
    __shared__ unsigned short Bs[128*32];
    const int mt = blockIdx.x, nt = blockIdx.y;
    const int row0 = mt*128, n0 = nt*128;
    const int rloc = row0 % TSEQ;
    const int seg = (rloc < 128) ? 0 : (rloc < 2176 ? 1 : 2);
    const unsigned short* Bp = Wb + (size_t)seg * NC * DIN;
    const int tid = threadIdx.x;
    const int wid = tid >> 6, lane = tid & 63;
    const int wr = wid >> 1, wc = wid & 1;
    const int lr = lane & 15, lg = lane >> 4;
    const int srow = lane >> 2;
    const int selem = (lane & 3) * 8;
    f32x4 acc[4][4];
#pragma unroll
    for (int m = 0; m < 4; ++m)
#pragma unroll
        for (int n = 0; n < 4; ++n) acc[m][n] = (f32x4){0.f,0.f,0.f,0.f};

    for (int kt = 0; kt < DIN/32; ++kt){
        const int k0 = kt*32;
        __syncthreads();
#pragma unroll
        for (int i = 0; i < 2; ++i){
            const int c = wid*2 + i;
            const int r = c*16 + srow;
            gload_lds16(&A [(size_t)(row0 + r)*DIN + k0 + selem], &As[c*512]);
            gload_lds16(&Bp[(size_t)(n0  + r)*DIN + k0 + selem], &Bs[c*512]);
        }
        __syncthreads();
        bf16x8 af[4], bfr[4];
#pragma unroll
        for (int m = 0; m < 4; ++m) af[m]  = *(const bf16x8*)&As[(wr*64 + m*16 + lr)*32 + lg*8];
#pragma unroll
        for (int n = 0; n < 4; ++n) bfr[n] = *(const bf16x8*)&Bs[(wc*64 + n*16 + lr)*32 + lg*8];
#pragma unroll
        for (int m = 0; m < 4; ++m)
#pragma unroll
            for (int n = 0; n < 4; ++n)
                acc[m][n] = __builtin_amdgcn_mfma_f32_16x16x32_bf16(af[m], bfr[n], acc[m][n], 0, 0, 0);
    }
    const int b_ = row0 / TSEQ;
    const int t0 = row0 - b_ * TSEQ;
#pragma unroll
    for (int m = 0; m < 4; ++m){
#pragma unroll
        for (int n = 0; n < 4; ++n){
            const int nglob = n0 + wc*64 + n*16 + lr;
            const float bs = bias[seg*NC + nglob];
            const int proj = nglob >> 9, hh = (nglob >> 6) & 7, e = nglob & 63;
            if (proj < 2){
                unsigned short* op = (proj == 0) ? qo : ko;
                const float scale = (proj == 0) ? 0.125f * L2E : 1.0f;
                const size_t ob = ((size_t)(b_*NH + hh) * TSEQ) * DD + e;
#pragma unroll
                for (int j = 0; j < 4; ++j){
                    const int t = t0 + wr*64 + m*16 + 4*lg + j;
                    op[ob + (size_t)t * DD] = f2bf((acc[m][n][j] + bs) * scale);
                }
            } else {
                unsigned short* vp = vt + ((size_t)(b_*NH + hh)*DD + e)*TSEQ;
                const int t = t0 + wr*64 + m*16 + 4*lg;
                u16x4 pk;
#pragma unroll
                for (int j = 0; j < 4; ++j) pk[j] = f2bf(acc[m][n][j] + bs);
                *(u16x4*)&vp[t] = pk;
            }
        }
    }
}

// Flash attention: 4 waves x 32 q-rows = 128 q-rows/block; split-K z=3 (12 tiles).
// 2-buffer LDS (K/V only, 32KB -> 4 blocks/CU, grid 864 fully resident, no tail).
// Swapped QK^T; P redistributed IN-REGISTER via ds_bpermute (no P-LDS, no P bank
// conflicts): target u32 p of pa[ks] comes from lane lr+16*(2(lg&1)+(p>>1)),
// reg u[2ks+(lg>>1)][p&1]. Raw v_exp_f32; deferred tril bias.
__global__ __launch_bounds__(256, 4) void k_attn(
    const unsigned short* __restrict__ Q,
    const unsigned short* __restrict__ K,
    const unsigned short* __restrict__ Vt,
    float* __restrict__ po0,
    float* __restrict__ po1,
    float* __restrict__ out2,
    float* __restrict__ pl)
{
    __shared__ unsigned short Ks[2][64*64];
    __shared__ unsigned short Vs[2][64*64];
    const int qtb = blockIdx.x;  // 18 (128-row q-tiles)
    const int bh  = blockIdx.y;  // 16
    const int z   = blockIdx.z;  // 3
    const int kt0 = z*12, kt1 = kt0 + 12;
    const int tid  = threadIdx.x;
    const int w    = tid >> 6;
    const int lane = tid & 63;
    const int lr = lane & 15, lg = lane >> 4;
    const size_t qkb = (size_t)bh * TSEQ * DD;
    const size_t vtb = (size_t)bh * DD * TSEQ;
    const int q0w = qtb*128 + w*32;
    const int kd  = qtb*2 + (w >> 1);    // wave-uniform diagonal k-tile

    const int rsub = lane >> 3;
    const int cgx  = (lane & 7) ^ rsub;  // inverse swizzle on global source
    const char* Kbase  = (const char*)(K  + qkb);
    const char* Vtbase = (const char*)(Vt + vtb);

    // bpermute lane indices (bytes): sl0 -> sg = 2*(lg&1), sl1 -> sg+1
    const int sl0 = (lr + ((lg & 1) << 5)) * 4;
    const int sl1 = sl0 + 64;
    const bool hi = (lg >> 1) != 0;

    bf16x8 aq[2][2];                     // [qg][ks]
#pragma unroll
    for (int qg = 0; qg < 2; ++qg)
#pragma unroll
        for (int ks = 0; ks < 2; ++ks)
            aq[qg][ks] = *(const bf16x8*)&Q[qkb + (size_t)(q0w + qg*16 + lr)*DD + ks*32 + lg*8];

    float lsum[2] = {0.f, 0.f};
    f32x4 o[2][4];
#pragma unroll
    for (int qg = 0; qg < 2; ++qg)
#pragma unroll
        for (int nd = 0; nd < 4; ++nd) o[qg][nd] = (f32x4){0.f,0.f,0.f,0.f};

    auto stage = [&](int kt, int b){
        const int kn = kt*64;
#pragma unroll
        for (int i = 0; i < 2; ++i){
            const int c = w*2 + i;
            const int r = c*8 + rsub;
            gload_lds16(Kbase  + (size_t)(kn + r)*128 + cgx*16,              &Ks[b][c*512]);
            gload_lds16(Vtbase + (size_t)r*(TSEQ*2) + (size_t)kn*2 + cgx*16, &Vs[b][c*512]);
        }
    };

    stage(kt0, 0);
    __syncthreads();

    int buf = 0;
    for (int kt = kt0; kt < kt1; ++kt){
        const int kc0 = kt*64;
        if (kt + 1 < kt1) stage(kt + 1, buf ^ 1);
        // QK^T for both q-groups (bk fragments shared, then dead)
        f32x4 s[2][4];
#pragma unroll
        for (int qg = 0; qg < 2; ++qg)
#pragma unroll
            for (int ns = 0; ns < 4; ++ns) s[qg][ns] = (f32x4){0.f,0.f,0.f,0.f};
#pragma unroll
        for (int ks = 0; ks < 2; ++ks)
#pragma unroll
            for (int ns = 0; ns < 4; ++ns){
                bf16x8 bk = *(const bf16x8*)&Ks[buf][(ns*16 + lr)*64 + (((4*ks + lg) ^ (lr & 7))*8)];
#pragma unroll
                for (int qg = 0; qg < 2; ++qg)
                    s[qg][ns] = __builtin_amdgcn_mfma_f32_16x16x32_bf16(bk, aq[qg][ks], s[qg][ns], 0, 0, 0);
            }
        // V fragments for this tile (shared by both q-groups)
        bf16x8 bv[2][4];
#pragma unroll
        for (int ks = 0; ks < 2; ++ks)
#pragma unroll
            for (int nd = 0; nd < 4; ++nd)
                bv[ks][nd] = *(const bf16x8*)&Vs[buf][(nd*16 + lr)*64 + (((4*ks + lg) ^ (lr & 7))*8)];
        // per q-group: softmax numerators -> packed u32 -> bpermute -> PV
#pragma unroll
        for (int qg = 0; qg < 2; ++qg){
            unsigned int u_[4][2];
            if (kt == kd){
                lsum[qg] *= EF;
#pragma unroll
                for (int nd = 0; nd < 4; ++nd)
#pragma unroll
                    for (int j = 0; j < 4; ++j) o[qg][nd][j] *= EF;
                const int qr = q0w + qg*16 + lr;
#pragma unroll
                for (int ns = 0; ns < 4; ++ns){
                    const int kb = kc0 + ns*16 + 4*lg;
                    float p0 = exp2raw(s[qg][ns][0] + ((kb + 0 <= qr) ? L2E : 0.f));
                    float p1 = exp2raw(s[qg][ns][1] + ((kb + 1 <= qr) ? L2E : 0.f));
                    float p2 = exp2raw(s[qg][ns][2] + ((kb + 2 <= qr) ? L2E : 0.f));
                    float p3 = exp2raw(s[qg][ns][3] + ((kb + 3 <= qr) ? L2E : 0.f));
                    lsum[qg] += (p0 + p1) + (p2 + p3);
                    u_[ns][0] = cvtpk(p0, p1);
                    u_[ns][1] = cvtpk(p2, p3);
                }
            } else {
#pragma unroll
                for (int ns = 0; ns < 4; ++ns){
                    float p0 = exp2raw(s[qg][ns][0]);
                    float p1 = exp2raw(s[qg][ns][1]);
                    float p2 = exp2raw(s[qg][ns][2]);
                    float p3 = exp2raw(s[qg][ns][3]);
                    lsum[qg] += (p0 + p1) + (p2 + p3);
                    u_[ns][0] = cvtpk(p0, p1);
                    u_[ns][1] = cvtpk(p2, p3);
                }
            }
#pragma unroll
            for (int ks = 0; ks < 2; ++ks){
                u32x4 wv;
                {
                    unsigned int a0 = (unsigned int)__builtin_amdgcn_ds_bpermute(sl0, (int)u_[2*ks+0][0]);
                    unsigned int b0 = (unsigned int)__builtin_amdgcn_ds_bpermute(sl0, (int)u_[2*ks+1][0]);
                    wv[0] = hi ? b0 : a0;
                    unsigned int a1 = (unsigned int)__builtin_amdgcn_ds_bpermute(sl0, (int)u_[2*ks+0][1]);
                    unsigned int b1 = (unsigned int)__builtin_amdgcn_ds_bpermute(sl0, (int)u_[2*ks+1][1]);
                    wv[1] = hi ? b1 : a1;
                    unsigned int a2 = (unsigned int)__builtin_amdgcn_ds_bpermute(sl1, (int)u_[2*ks+0][0]);
                    unsigned int b2 = (unsigned int)__builtin_amdgcn_ds_bpermute(sl1, (int)u_[2*ks+1][0]);
                    wv[2] = hi ? b2 : a2;
                    unsigned int a3 = (unsigned int)__builtin_amdgcn_ds_bpermute(sl1, (int)u_[2*ks+0][1]);
                    unsigned int b3 = (unsigned int)__builtin_amdgcn_ds_bpermute(sl1, (int)u_[2*ks+1][1]);
                    wv[3] = hi ? b3 : a3;
                }
                bf16x8 pa = __builtin_bit_cast(bf16x8, wv);
#pragma unroll
                for (int nd = 0; nd < 4; ++nd)
                    o[qg][nd] = __builtin_amdgcn_mfma_f32_16x16x32_bf16(pa, bv[ks][nd], o[qg][nd], 0, 0, 0);
            }
        }
        __syncthreads();
        buf ^= 1;
    }
    if (kd >= kt1){
#pragma unroll
        for (int qg = 0; qg < 2; ++qg){
            lsum[qg] *= EF;
#pragma unroll
            for (int nd = 0; nd < 4; ++nd)
#pragma unroll
                for (int j = 0; j < 4; ++j) o[qg][nd][j] *= EF;
        }
    }
    // lsum reduce over lg groups (q-row = qg*16+lr)
#pragma unroll
    for (int qg = 0; qg < 2; ++qg){
        lsum[qg] += __shfl_xor(lsum[qg], 16);
        lsum[qg] += __shfl_xor(lsum[qg], 32);
    }
    const int pbase = ((z*16 + bh)*18 + qtb)*128 + w*32;
    if (lg == 0){
        pl[pbase + 0*16 + lr] = lsum[0];
        pl[pbase + 1*16 + lr] = lsum[1];
    }
    if (z < 2){
        float* po = (z == 0) ? po0 : po1;
        const size_t tb = ((size_t)(bh*18 + qtb)*128 + w*32) * 64;
#pragma unroll
        for (int qg = 0; qg < 2; ++qg)
#pragma unroll
            for (int j = 0; j < 4; ++j)
#pragma unroll
                for (int nd = 0; nd < 4; ++nd)
                    po[tb + (size_t)(qg*16 + 4*lg + j)*64 + nd*16 + lr] = o[qg][nd][j];
    } else {
        const int b_ = bh >> 3, hh = bh & 7;
#pragma unroll
        for (int qg = 0; qg < 2; ++qg){
#pragma unroll
            for (int j = 0; j < 4; ++j){
                const int t = q0w + qg*16 + 4*lg + j;
                const size_t ob = ((size_t)(b_*TSEQ + t))*512 + hh*64;
#pragma unroll
                for (int nd = 0; nd < 4; ++nd)
                    out2[ob + nd*16 + lr] = o[qg][nd][j];
            }
        }
    }
}

// out = (po0 + po1 + out(po2)) / (pl0 + pl1 + pl2); po2 lives in out-layout
__global__ __launch_bounds__(256) void k_comb(
    const float* __restrict__ po0, const float* __restrict__ po1,
    const float* __restrict__ pl, float* __restrict__ out)
{
    const int qt = blockIdx.x, bh = blockIdx.y;   // 36 x 16
    const int b_ = bh >> 3, hh = bh & 7;
    const int tid = threadIdx.x;
    const int row = tid >> 2;            // 0..63
    const int c0  = (tid & 3) * 16;
    const int t128  = qt >> 1;
    const int rowin = (qt & 1)*64 + row;
    const int plb = (bh*18 + t128)*128 + rowin;
    const float inv = 1.0f / (pl[plb] + pl[(16*18*128) + plb] + pl[(2*16*18*128) + plb]);
    const size_t tb = ((size_t)(bh*18 + t128)*128 + rowin)*64 + c0;
    const size_t ob = ((size_t)(b_*TSEQ + qt*64 + row))*512 + hh*64 + c0;
#pragma unroll
    for (int i = 0; i < 4; ++i){
        f32x4 a = *(const f32x4*)&po0[tb + i*4];
        f32x4 b = *(const f32x4*)&po1[tb + i*4];
        f32x4 c = *(const f32x4*)&out[ob + i*4];
        f32x4 r;
#pragma unroll
        for (int j = 0; j < 4; ++j) r[j] = (a[j] + b[j] + c[j]) * inv;
        *(f32x4*)&out[ob + i*4] = r;
    }
}

extern "C" void kernel_launch(void* const* d_in, const int* in_sizes, int n_in,
                              void* d_out, int out_size, void* d_ws, size_t ws_size,
                              hipStream_t stream)
{
    const float* x     = (const float*)d_in[0];
    const float* ln_g  = (const float*)d_in[1];
    const float* ln_b  = (const float*)d_in[2];
    const float* ln_gs = (const float*)d_in[3];
    const float* ln_bs = (const float*)d_in[4];
    const float* ln_ge = (const float*)d_in[5];
    const float* ln_be = (const float*)d_in[6];
    const float* Wq    = (const float*)d_in[7];
    const float* Wk    = (const float*)d_in[8];
    const float* Wv    = (const float*)d_in[9];
    const float* Wq_s  = (const float*)d_in[10];
    const float* Wk_s  = (const float*)d_in[11];
    const float* Wv_s  = (const float*)d_in[12];
    const float* Wq_e  = (const float*)d_in[13];
    const float* Wk_e  = (const float*)d_in[14];
    const float* Wv_e  = (const float*)d_in[15];

    uint8_t* w = (uint8_t*)d_ws;
    unsigned short* nrm = (unsigned short*)(w);                 //  9,437,184 B
    unsigned short* wb  = (unsigned short*)(w + 9437184);       //  9,437,184 B
    float*          bia = (float*)        (w + 18874368);       //     18,432 B
    unsigned short* q_  = (unsigned short*)(w + 18892800);      //  4,718,592 B
    unsigned short* k_  = (unsigned short*)(w + 23611392);      //  4,718,592 B
    unsigned short* vt_ = (unsigned short*)(w + 28329984);      //  4,718,592 B (end 33,048,576)
    float*          pl  = (float*)        (w + 33048576);       //    442,368 B (end 33,490,944)
    float*          po0 = (float*)        (w);                  //  9,437,184 B -- reuses nrm (dead after k_gemm)
    float*          po1 = (float*)        (w + 9437184);        //  9,437,184 B -- reuses wb  (dead after k_gemm)

    WArgs wa;
    wa.W[0] = Wq_s; wa.W[1] = Wk_s; wa.W[2] = Wv_s;
    wa.W[3] = Wq;   wa.W[4] = Wk;   wa.W[5] = Wv;
    wa.W[6] = Wq_e; wa.W[7] = Wk_e; wa.W[8] = Wv_e;
    wa.g[0] = ln_gs; wa.g[1] = ln_g; wa.g[2] = ln_ge;
    wa.bv[0] = ln_bs; wa.bv[1] = ln_b; wa.bv[2] = ln_be;

    float* out = (float*)d_out;
    k_pre <<<dim3(5832),      dim3(256), 0, stream>>>(wa, x, wb, bia, nrm);
    k_gemm<<<dim3(36, 12),    dim3(256), 0, stream>>>(nrm, wb, bia, q_, k_, vt_);
    k_attn<<<dim3(18, 16, 3), dim3(256), 0, stream>>>(q_, k_, vt_, po0, po1, out, pl);
    k_comb<<<dim3(36, 16),    dim3(256), 0, stream>>>(po0, po1, pl, out);
}

// Round 12
// 99.571 us; speedup vs baseline: 1.1790x; 1.1790x over previous
//
#include <hip/hip_runtime.h>

#define TSEQ 2304
#define DIN  1024
#define NH   8
#define DD   64
#define NC   1536
#define MROWS 4608
#define L2E  1.44269504f
#define EF   2.71828183f

typedef __attribute__((ext_vector_type(8))) short bf16x8;
typedef __attribute__((ext_vector_type(4))) float f32x4;
typedef __attribute__((ext_vector_type(4))) unsigned short u16x4;

__device__ __forceinline__ unsigned short f2bf(float f){
    union { float f; unsigned int u; } x; x.f = f;
    unsigned int r = x.u + 0x7FFFu + ((x.u >> 16) & 1u);
    return (unsigned short)(r >> 16);
}

// raw v_exp_f32: D = 2^S0, no libm guard code (inputs bounded +-10 here)
__device__ __forceinline__ float exp2raw(float x){
    float r;
    asm("v_exp_f32 %0, %1" : "=v"(r) : "v"(x));
    return r;
}

// two f32 -> packed [bf16(b):bf16(a)] in one VALU op
__device__ __forceinline__ unsigned int cvtpk(float a, float b){
    unsigned int r;
    asm("v_cvt_pk_bf16_f32 %0, %1, %2" : "=v"(r) : "v"(a), "v"(b));
    return r;
}

__device__ __forceinline__ void gload_lds16(const void* g, void* l){
    __builtin_amdgcn_global_load_lds(
        (const __attribute__((address_space(1))) void*)g,
        (__attribute__((address_space(3))) void*)l, 16, 0, 0);
}

struct WArgs {
    const float* W[9];   // [seg*3+proj], seg0=s, seg1=m, seg2=e; proj0=q,1=k,2=v
    const float* g[3];
    const float* bv[3];
};

// Fused preprocessing: blocks [0,1152) build Wb, [1152,1224) bias, [1224,5832) LN
__global__ __launch_bounds__(256) void k_pre(WArgs a, const float* __restrict__ x,
                                             unsigned short* __restrict__ wb,
                                             float* __restrict__ bias,
                                             unsigned short* __restrict__ nrm)
{
    __shared__ float lds[64][65];
    __shared__ float red[4][64];
    __shared__ float r1[4], r2[4];
    const int bid = blockIdx.x;
    const int tid = threadIdx.x;
    if (bid < 1152){
        const int dt = bid & 15, h = (bid >> 4) & 7, sp = bid >> 7;
        const int seg = sp / 3, proj = sp % 3;
        const float* W = a.W[seg*3 + proj];
        const float* g = a.g[seg];
        const int d0 = dt * 64;
        {
            const int e = tid & 63, rq = tid >> 6;
#pragma unroll
            for (int rr = 0; rr < 16; ++rr){
                const int dl = rr*4 + rq;
                lds[dl][e] = W[((size_t)h*DIN + d0 + dl)*DD + e];
            }
        }
        __syncthreads();
        {
            const int dl = tid & 63, eq = tid >> 6;
            const int n0 = proj*512 + h*64;
            const float gv = g[h*DIN + d0 + dl];
#pragma unroll
            for (int rr = 0; rr < 16; ++rr){
                const int el = eq*16 + rr;
                wb[((size_t)seg*NC + n0 + el)*DIN + d0 + dl] = f2bf(lds[dl][el] * gv);
            }
        }
    } else if (bid < 1224){
        const int u = bid - 1152;
        const int h = u & 7, sp = u >> 3;
        const int seg = sp / 3, proj = sp % 3;
        const float* W  = a.W[seg*3 + proj];
        const float* bv = a.bv[seg];
        const int e = tid & 63, dc = tid >> 6;
        float sum = 0.f;
        for (int i = 0; i < 256; ++i){
            const int d = dc*256 + i;
            sum += bv[h*DIN + d] * W[((size_t)h*DIN + d)*DD + e];
        }
        red[dc][e] = sum;
        __syncthreads();
        if (dc == 0)
            bias[seg*NC + proj*512 + h*64 + e] = red[0][e] + red[1][e] + red[2][e] + red[3][e];
    } else {
        const int row = bid - 1224;
        const float* xr = x + (size_t)row * DIN;
        f32x4 v = *(const f32x4*)&xr[tid*4];
        float s1 = v[0]+v[1]+v[2]+v[3];
        float s2 = v[0]*v[0]+v[1]*v[1]+v[2]*v[2]+v[3]*v[3];
#pragma unroll
        for (int m = 1; m < 64; m <<= 1){ s1 += __shfl_xor(s1, m); s2 += __shfl_xor(s2, m); }
        const int wid = tid >> 6;
        if ((tid & 63) == 0){ r1[wid] = s1; r2[wid] = s2; }
        __syncthreads();
        s1 = r1[0]+r1[1]+r1[2]+r1[3];
        s2 = r2[0]+r2[1]+r2[2]+r2[3];
        const float mean = s1 * (1.f/1024.f);
        const float var  = s2 * (1.f/1024.f) - mean*mean;
        const float rstd = rsqrtf(var + 1e-5f);
        u16x4 ov;
#pragma unroll
        for (int j = 0; j < 4; ++j) ov[j] = f2bf((v[j]-mean)*rstd);
        *(u16x4*)&nrm[(size_t)row*DIN + tid*4] = ov;
    }
}

// C[4608][1536] = nrm @ Wb[seg]^T + bias; q,k scattered to [b][h][t][64];
// V written DIRECTLY TRANSPOSED to vt[b][h][e][t]. q pre-scaled by 0.125*log2e.
// BK=64 (16 iters, half the barriers of BK=32). LDS [128][64] with XOR slot
// swizzle: physical 16B slot p of row r holds logical slot p^(r&7); staged via
// pre-swizzled global source (linear LDS dest), read with matching XOR ->
// fragment b128 reads spread uniformly over all 8 slot positions.
__global__ __launch_bounds__(256) void k_gemm(
    const unsigned short* __restrict__ A,
    const unsigned short* __restrict__ Wb,
    const float* __restrict__ bias,
    unsigned short* __restrict__ qo,
    unsigned short* __restrict__ ko,
    unsigned short* __restrict__ vt)
{
    __shared__ unsigned short As[128*64];
    __shared__ unsigned short Bs[128*64];
    const int mt = blockIdx.x, nt = blockIdx.y;
    const int row0 = mt*128, n0 = nt*128;
    const int rloc = row0 % TSEQ;
    const int seg = (rloc < 128) ? 0 : (rloc < 2176 ? 1 : 2);
    const unsigned short* Bp = Wb + (size_t)seg * NC * DIN;
    const int tid = threadIdx.x;
    const int wid = tid >> 6, lane = tid & 63;
    const int wr = wid >> 1, wc = wid & 1;
    const int lr = lane & 15, lg = lane >> 4;
    // staging: chunk c = 8 rows x 64 elems (1024B); lane covers row c*8+(l>>3),
    // global slot (l&7)^(l>>3), LDS linear dest c*512 shorts + l*16B
    const int rsub = lane >> 3;
    const int cgx  = (lane & 7) ^ rsub;
    f32x4 acc[4][4];
#pragma unroll
    for (int m = 0; m < 4; ++m)
#pragma unroll
        for (int n = 0; n < 4; ++n) acc[m][n] = (f32x4){0.f,0.f,0.f,0.f};

    for (int kt = 0; kt < DIN/64; ++kt){
        const int k0 = kt*64;
        __syncthreads();
#pragma unroll
        for (int i = 0; i < 4; ++i){
            const int c = wid*4 + i;
            const int r = c*8 + rsub;
            gload_lds16(&A [(size_t)(row0 + r)*DIN + k0 + cgx*8], &As[c*512]);
            gload_lds16(&Bp[(size_t)(n0  + r)*DIN + k0 + cgx*8], &Bs[c*512]);
        }
        __syncthreads();
#pragma unroll
        for (int ks = 0; ks < 2; ++ks){
            bf16x8 af[4], bfr[4];
#pragma unroll
            for (int m = 0; m < 4; ++m)
                af[m]  = *(const bf16x8*)&As[(wr*64 + m*16 + lr)*64 + (((ks*4 + lg) ^ (lr & 7))*8)];
#pragma unroll
            for (int n = 0; n < 4; ++n)
                bfr[n] = *(const bf16x8*)&Bs[(wc*64 + n*16 + lr)*64 + (((ks*4 + lg) ^ (lr & 7))*8)];
#pragma unroll
            for (int m = 0; m < 4; ++m)
#pragma unroll
                for (int n = 0; n < 4; ++n)
                    acc[m][n] = __builtin_amdgcn_mfma_f32_16x16x32_bf16(af[m], bfr[n], acc[m][n], 0, 0, 0);
        }
    }
    const int b_ = row0 / TSEQ;
    const int t0 = row0 - b_ * TSEQ;
#pragma unroll
    for (int m = 0; m < 4; ++m){
#pragma unroll
        for (int n = 0; n < 4; ++n){
            const int nglob = n0 + wc*64 + n*16 + lr;
            const float bs = bias[seg*NC + nglob];
            const int proj = nglob >> 9, hh = (nglob >> 6) & 7, e = nglob & 63;
            if (proj < 2){
                unsigned short* op = (proj == 0) ? qo : ko;
                const float scale = (proj == 0) ? 0.125f * L2E : 1.0f;
                const size_t ob = ((size_t)(b_*NH + hh) * TSEQ) * DD + e;
#pragma unroll
                for (int j = 0; j < 4; ++j){
                    const int t = t0 + wr*64 + m*16 + 4*lg + j;
                    op[ob + (size_t)t * DD] = f2bf((acc[m][n][j] + bs) * scale);
                }
            } else {
                unsigned short* vp = vt + ((size_t)(b_*NH + hh)*DD + e)*TSEQ;
                const int t = t0 + wr*64 + m*16 + 4*lg;
                u16x4 pk;
#pragma unroll
                for (int j = 0; j < 4; ++j) pk[j] = f2bf(acc[m][n][j] + bs);
                *(u16x4*)&vp[t] = pk;
            }
        }
    }
}

// Flash attention: 4 waves x 32 q-rows = 128 q-rows/block; split-K z=3 (12 tiles).
// 2-buffer LDS, prefetch-1, plain __syncthreads. Swapped QK^T; bk/bv fragments
// loaded once per tile, reused across both q-groups. Raw v_exp_f32 softmax
// (exp2-domain, no libm guards). cvt_pk packs P. Deferred tril bias.
__global__ __launch_bounds__(256) void k_attn(
    const unsigned short* __restrict__ Q,
    const unsigned short* __restrict__ K,
    const unsigned short* __restrict__ Vt,
    float* __restrict__ po0,
    float* __restrict__ po1,
    float* __restrict__ out2,
    float* __restrict__ pl)
{
    __shared__ unsigned short Ks[2][64*64];
    __shared__ unsigned short Vs[2][64*64];
    __shared__ unsigned short Plds[4][32][72];
    const int qtb = blockIdx.x;  // 18 (128-row q-tiles)
    const int bh  = blockIdx.y;  // 16
    const int z   = blockIdx.z;  // 3
    const int kt0 = z*12, kt1 = kt0 + 12;
    const int tid  = threadIdx.x;
    const int w    = tid >> 6;
    const int lane = tid & 63;
    const int lr = lane & 15, lg = lane >> 4;
    const size_t qkb = (size_t)bh * TSEQ * DD;
    const size_t vtb = (size_t)bh * DD * TSEQ;
    const int q0w = qtb*128 + w*32;
    const int kd  = qtb*2 + (w >> 1);    // wave-uniform diagonal k-tile

    const int rsub = lane >> 3;
    const int cgx  = (lane & 7) ^ rsub;  // inverse swizzle on global source
    const char* Kbase  = (const char*)(K  + qkb);
    const char* Vtbase = (const char*)(Vt + vtb);

    bf16x8 aq[2][2];                     // [qg][ks]
#pragma unroll
    for (int qg = 0; qg < 2; ++qg)
#pragma unroll
        for (int ks = 0; ks < 2; ++ks)
            aq[qg][ks] = *(const bf16x8*)&Q[qkb + (size_t)(q0w + qg*16 + lr)*DD + ks*32 + lg*8];

    float lsum[2] = {0.f, 0.f};
    f32x4 o[2][4];
#pragma unroll
    for (int qg = 0; qg < 2; ++qg)
#pragma unroll
        for (int nd = 0; nd < 4; ++nd) o[qg][nd] = (f32x4){0.f,0.f,0.f,0.f};

    auto stage = [&](int kt, int b){
        const int kn = kt*64;
#pragma unroll
        for (int i = 0; i < 2; ++i){
            const int c = w*2 + i;
            const int r = c*8 + rsub;
            gload_lds16(Kbase  + (size_t)(kn + r)*128 + cgx*16,              &Ks[b][c*512]);
            gload_lds16(Vtbase + (size_t)r*(TSEQ*2) + (size_t)kn*2 + cgx*16, &Vs[b][c*512]);
        }
    };

    stage(kt0, 0);
    __syncthreads();

    unsigned int* PldsW = (unsigned int*)&Plds[w][0][0];  // row stride 36 u32

    int buf = 0;
    for (int kt = kt0; kt < kt1; ++kt){
        const int kc0 = kt*64;
        if (kt + 1 < kt1) stage(kt + 1, buf ^ 1);
        // K fragments once per tile, shared by both q-groups
        bf16x8 bk[2][4];
#pragma unroll
        for (int ks = 0; ks < 2; ++ks)
#pragma unroll
            for (int ns = 0; ns < 4; ++ns)
                bk[ks][ns] = *(const bf16x8*)&Ks[buf][(ns*16 + lr)*64 + (((4*ks + lg) ^ (lr & 7))*8)];
        // QK^T swapped: s[qg][ns][j] = S[q0w+qg*16+lr][kc0 + ns*16 + 4*lg + j]
        f32x4 s[2][4];
#pragma unroll
        for (int qg = 0; qg < 2; ++qg)
#pragma unroll
            for (int ns = 0; ns < 4; ++ns) s[qg][ns] = (f32x4){0.f,0.f,0.f,0.f};
#pragma unroll
        for (int qg = 0; qg < 2; ++qg)
#pragma unroll
            for (int ks = 0; ks < 2; ++ks)
#pragma unroll
                for (int ns = 0; ns < 4; ++ns)
                    s[qg][ns] = __builtin_amdgcn_mfma_f32_16x16x32_bf16(bk[ks][ns], aq[qg][ks], s[qg][ns], 0, 0, 0);
        // softmax numerators
        if (kt == kd){
#pragma unroll
            for (int qg = 0; qg < 2; ++qg){
                lsum[qg] *= EF;
#pragma unroll
                for (int nd = 0; nd < 4; ++nd)
#pragma unroll
                    for (int j = 0; j < 4; ++j) o[qg][nd][j] *= EF;
                const int qr = q0w + qg*16 + lr;
#pragma unroll
                for (int ns = 0; ns < 4; ++ns){
                    const int kb = kc0 + ns*16 + 4*lg;
                    float p0 = exp2raw(s[qg][ns][0] + ((kb + 0 <= qr) ? L2E : 0.f));
                    float p1 = exp2raw(s[qg][ns][1] + ((kb + 1 <= qr) ? L2E : 0.f));
                    float p2 = exp2raw(s[qg][ns][2] + ((kb + 2 <= qr) ? L2E : 0.f));
                    float p3 = exp2raw(s[qg][ns][3] + ((kb + 3 <= qr) ? L2E : 0.f));
                    lsum[qg] += (p0 + p1) + (p2 + p3);
                    PldsW[(qg*16 + lr)*36 + ns*8 + 2*lg + 0] = cvtpk(p0, p1);
                    PldsW[(qg*16 + lr)*36 + ns*8 + 2*lg + 1] = cvtpk(p2, p3);
                }
            }
        } else {
#pragma unroll
            for (int qg = 0; qg < 2; ++qg){
#pragma unroll
                for (int ns = 0; ns < 4; ++ns){
                    float p0 = exp2raw(s[qg][ns][0]);
                    float p1 = exp2raw(s[qg][ns][1]);
                    float p2 = exp2raw(s[qg][ns][2]);
                    float p3 = exp2raw(s[qg][ns][3]);
                    lsum[qg] += (p0 + p1) + (p2 + p3);
                    PldsW[(qg*16 + lr)*36 + ns*8 + 2*lg + 0] = cvtpk(p0, p1);
                    PldsW[(qg*16 + lr)*36 + ns*8 + 2*lg + 1] = cvtpk(p2, p3);
                }
            }
        }
        // PV: V fragments once per tile, shared by both q-groups
        bf16x8 bv[2][4];
#pragma unroll
        for (int ks = 0; ks < 2; ++ks)
#pragma unroll
            for (int nd = 0; nd < 4; ++nd)
                bv[ks][nd] = *(const bf16x8*)&Vs[buf][(nd*16 + lr)*64 + (((4*ks + lg) ^ (lr & 7))*8)];
#pragma unroll
        for (int qg = 0; qg < 2; ++qg){
            bf16x8 pa0 = *(const bf16x8*)&Plds[w][qg*16 + lr][0*32 + lg*8];
            bf16x8 pa1 = *(const bf16x8*)&Plds[w][qg*16 + lr][1*32 + lg*8];
#pragma unroll
            for (int nd = 0; nd < 4; ++nd){
                o[qg][nd] = __builtin_amdgcn_mfma_f32_16x16x32_bf16(pa0, bv[0][nd], o[qg][nd], 0, 0, 0);
                o[qg][nd] = __builtin_amdgcn_mfma_f32_16x16x32_bf16(pa1, bv[1][nd], o[qg][nd], 0, 0, 0);
            }
        }
        __syncthreads();
        buf ^= 1;
    }
    if (kd >= kt1){
#pragma unroll
        for (int qg = 0; qg < 2; ++qg){
            lsum[qg] *= EF;
#pragma unroll
            for (int nd = 0; nd < 4; ++nd)
#pragma unroll
                for (int j = 0; j < 4; ++j) o[qg][nd][j] *= EF;
        }
    }
    // lsum reduce over lg groups (q-row = qg*16+lr)
#pragma unroll
    for (int qg = 0; qg < 2; ++qg){
        lsum[qg] += __shfl_xor(lsum[qg], 16);
        lsum[qg] += __shfl_xor(lsum[qg], 32);
    }
    const int pbase = ((z*16 + bh)*18 + qtb)*128 + w*32;
    if (lg == 0){
        pl[pbase + 0*16 + lr] = lsum[0];
        pl[pbase + 1*16 + lr] = lsum[1];
    }
    if (z < 2){
        float* po = (z == 0) ? po0 : po1;
        const size_t tb = ((size_t)(bh*18 + qtb)*128 + w*32) * 64;
#pragma unroll
        for (int qg = 0; qg < 2; ++qg)
#pragma unroll
            for (int j = 0; j < 4; ++j)
#pragma unroll
                for (int nd = 0; nd < 4; ++nd)
                    po[tb + (size_t)(qg*16 + 4*lg + j)*64 + nd*16 + lr] = o[qg][nd][j];
    } else {
        const int b_ = bh >> 3, hh = bh & 7;
#pragma unroll
        for (int qg = 0; qg < 2; ++qg){
#pragma unroll
            for (int j = 0; j < 4; ++j){
                const int t = q0w + qg*16 + 4*lg + j;
                const size_t ob = ((size_t)(b_*TSEQ + t))*512 + hh*64;
#pragma unroll
                for (int nd = 0; nd < 4; ++nd)
                    out2[ob + nd*16 + lr] = o[qg][nd][j];
            }
        }
    }
}

// out = (po0 + po1 + out(po2)) / (pl0 + pl1 + pl2); po2 lives in out-layout
__global__ __launch_bounds__(256) void k_comb(
    const float* __restrict__ po0, const float* __restrict__ po1,
    const float* __restrict__ pl, float* __restrict__ out)
{
    const int qt = blockIdx.x, bh = blockIdx.y;   // 36 x 16
    const int b_ = bh >> 3, hh = bh & 7;
    const int tid = threadIdx.x;
    const int row = tid >> 2;            // 0..63
    const int c0  = (tid & 3) * 16;
    const int t128  = qt >> 1;
    const int rowin = (qt & 1)*64 + row;
    const int plb = (bh*18 + t128)*128 + rowin;
    const float inv = 1.0f / (pl[plb] + pl[(16*18*128) + plb] + pl[(2*16*18*128) + plb]);
    const size_t tb = ((size_t)(bh*18 + t128)*128 + rowin)*64 + c0;
    const size_t ob = ((size_t)(b_*TSEQ + qt*64 + row))*512 + hh*64 + c0;
#pragma unroll
    for (int i = 0; i < 4; ++i){
        f32x4 a = *(const f32x4*)&po0[tb + i*4];
        f32x4 b = *(const f32x4*)&po1[tb + i*4];
        f32x4 c = *(const f32x4*)&out[ob + i*4];
        f32x4 r;
#pragma unroll
        for (int j = 0; j < 4; ++j) r[j] = (a[j] + b[j] + c[j]) * inv;
        *(f32x4*)&out[ob + i*4] = r;
    }
}

extern "C" void kernel_launch(void* const* d_in, const int* in_sizes, int n_in,
                              void* d_out, int out_size, void* d_ws, size_t ws_size,
                              hipStream_t stream)
{
    const float* x     = (const float*)d_in[0];
    const float* ln_g  = (const float*)d_in[1];
    const float* ln_b  = (const float*)d_in[2];
    const float* ln_gs = (const float*)d_in[3];
    const float* ln_bs = (const float*)d_in[4];
    const float* ln_ge = (const float*)d_in[5];
    const float* ln_be = (const float*)d_in[6];
    const float* Wq    = (const float*)d_in[7];
    const float* Wk    = (const float*)d_in[8];
    const float* Wv    = (const float*)d_in[9];
    const float* Wq_s  = (const float*)d_in[10];
    const float* Wk_s  = (const float*)d_in[11];
    const float* Wv_s  = (const float*)d_in[12];
    const float* Wq_e  = (const float*)d_in[13];
    const float* Wk_e  = (const float*)d_in[14];
    const float* Wv_e  = (const float*)d_in[15];

    uint8_t* w = (uint8_t*)d_ws;
    unsigned short* nrm = (unsigned short*)(w);                 //  9,437,184 B
    unsigned short* wb  = (unsigned short*)(w + 9437184);       //  9,437,184 B
    float*          bia = (float*)        (w + 18874368);       //     18,432 B
    unsigned short* q_  = (unsigned short*)(w + 18892800);      //  4,718,592 B
    unsigned short* k_  = (unsigned short*)(w + 23611392);      //  4,718,592 B
    unsigned short* vt_ = (unsigned short*)(w + 28329984);      //  4,718,592 B (end 33,048,576)
    float*          pl  = (float*)        (w + 33048576);       //    442,368 B (end 33,490,944)
    float*          po0 = (float*)        (w);                  //  9,437,184 B -- reuses nrm (dead after k_gemm)
    float*          po1 = (float*)        (w + 9437184);        //  9,437,184 B -- reuses wb  (dead after k_gemm)

    WArgs wa;
    wa.W[0] = Wq_s; wa.W[1] = Wk_s; wa.W[2] = Wv_s;
    wa.W[3] = Wq;   wa.W[4] = Wk;   wa.W[5] = Wv;
    wa.W[6] = Wq_e; wa.W[7] = Wk_e; wa.W[8] = Wv_e;
    wa.g[0] = ln_gs; wa.g[1] = ln_g; wa.g[2] = ln_ge;
    wa.bv[0] = ln_bs; wa.bv[1] = ln_b; wa.bv[2] = ln_be;

    float* out = (float*)d_out;
    k_pre <<<dim3(5832),      dim3(256), 0, stream>>>(wa, x, wb, bia, nrm);
    k_gemm<<<dim3(36, 12),    dim3(256), 0, stream>>>(nrm, wb, bia, q_, k_, vt_);
    k_attn<<<dim3(18, 16, 3), dim3(256), 0, stream>>>(q_, k_, vt_, po0, po1, out, pl);
    k_comb<<<dim3(36, 16),    dim3(256), 0, stream>>>(po0, po1, pl, out);
}

// Round 13
// 97.394 us; speedup vs baseline: 1.2053x; 1.0224x over previous
//
#include <hip/hip_runtime.h>

#define TSEQ 2304
#define DIN  1024
#define NH   8
#define DD   64
#define NC   1536
#define MROWS 4608
#define L2E  1.44269504f
#define EF   2.71828183f

typedef __attribute__((ext_vector_type(8))) short bf16x8;
typedef __attribute__((ext_vector_type(4))) float f32x4;
typedef __attribute__((ext_vector_type(16))) float f32x16;
typedef __attribute__((ext_vector_type(4))) unsigned short u16x4;
typedef __attribute__((ext_vector_type(4))) unsigned int u32x4;

__device__ __forceinline__ unsigned short f2bf(float f){
    union { float f; unsigned int u; } x; x.f = f;
    unsigned int r = x.u + 0x7FFFu + ((x.u >> 16) & 1u);
    return (unsigned short)(r >> 16);
}

// raw v_exp_f32: D = 2^S0, no libm guard code (inputs bounded +-10 here)
__device__ __forceinline__ float exp2raw(float x){
    float r;
    asm("v_exp_f32 %0, %1" : "=v"(r) : "v"(x));
    return r;
}

// two f32 -> packed [bf16(b):bf16(a)] in one VALU op
__device__ __forceinline__ unsigned int cvtpk(float a, float b){
    unsigned int r;
    asm("v_cvt_pk_bf16_f32 %0, %1, %2" : "=v"(r) : "v"(a), "v"(b));
    return r;
}

__device__ __forceinline__ void gload_lds16(const void* g, void* l){
    __builtin_amdgcn_global_load_lds(
        (const __attribute__((address_space(1))) void*)g,
        (__attribute__((address_space(3))) void*)l, 16, 0, 0);
}

struct WArgs {
    const float* W[9];   // [seg*3+proj], seg0=s, seg1=m, seg2=e; proj0=q,1=k,2=v
    const float* g[3];
    const float* bv[3];
};

// Fused preprocessing: blocks [0,1152) build Wb, [1152,1224) bias, [1224,5832) LN
__global__ __launch_bounds__(256) void k_pre(WArgs a, const float* __restrict__ x,
                                             unsigned short* __restrict__ wb,
                                             float* __restrict__ bias,
                                             unsigned short* __restrict__ nrm)
{
    __shared__ float lds[64][65];
    __shared__ float red[4][64];
    __shared__ float r1[4], r2[4];
    const int bid = blockIdx.x;
    const int tid = threadIdx.x;
    if (bid < 1152){
        const int dt = bid & 15, h = (bid >> 4) & 7, sp = bid >> 7;
        const int seg = sp / 3, proj = sp % 3;
        const float* W = a.W[seg*3 + proj];
        const float* g = a.g[seg];
        const int d0 = dt * 64;
        {
            const int e = tid & 63, rq = tid >> 6;
#pragma unroll
            for (int rr = 0; rr < 16; ++rr){
                const int dl = rr*4 + rq;
                lds[dl][e] = W[((size_t)h*DIN + d0 + dl)*DD + e];
            }
        }
        __syncthreads();
        {
            const int dl = tid & 63, eq = tid >> 6;
            const int n0 = proj*512 + h*64;
            const float gv = g[h*DIN + d0 + dl];
#pragma unroll
            for (int rr = 0; rr < 16; ++rr){
                const int el = eq*16 + rr;
                wb[((size_t)seg*NC + n0 + el)*DIN + d0 + dl] = f2bf(lds[dl][el] * gv);
            }
        }
    } else if (bid < 1224){
        const int u = bid - 1152;
        const int h = u & 7, sp = u >> 3;
        const int seg = sp / 3, proj = sp % 3;
        const float* W  = a.W[seg*3 + proj];
        const float* bv = a.bv[seg];
        const int e = tid & 63, dc = tid >> 6;
        float sum = 0.f;
        for (int i = 0; i < 256; ++i){
            const int d = dc*256 + i;
            sum += bv[h*DIN + d] * W[((size_t)h*DIN + d)*DD + e];
        }
        red[dc][e] = sum;
        __syncthreads();
        if (dc == 0)
            bias[seg*NC + proj*512 + h*64 + e] = red[0][e] + red[1][e] + red[2][e] + red[3][e];
    } else {
        const int row = bid - 1224;
        const float* xr = x + (size_t)row * DIN;
        f32x4 v = *(const f32x4*)&xr[tid*4];
        float s1 = v[0]+v[1]+v[2]+v[3];
        float s2 = v[0]*v[0]+v[1]*v[1]+v[2]*v[2]+v[3]*v[3];
#pragma unroll
        for (int m = 1; m < 64; m <<= 1){ s1 += __shfl_xor(s1, m); s2 += __shfl_xor(s2, m); }
        const int wid = tid >> 6;
        if ((tid & 63) == 0){ r1[wid] = s1; r2[wid] = s2; }
        __syncthreads();
        s1 = r1[0]+r1[1]+r1[2]+r1[3];
        s2 = r2[0]+r2[1]+r2[2]+r2[3];
        const float mean = s1 * (1.f/1024.f);
        const float var  = s2 * (1.f/1024.f) - mean*mean;
        const float rstd = rsqrtf(var + 1e-5f);
        u16x4 ov;
#pragma unroll
        for (int j = 0; j < 4; ++j) ov[j] = f2bf((v[j]-mean)*rstd);
        *(u16x4*)&nrm[(size_t)row*DIN + tid*4] = ov;
    }
}

// C[4608][1536] = nrm @ Wb[seg]^T + bias; q,k scattered to [b][h][t][64];
// V written DIRECTLY TRANSPOSED to vt[b][h][e][t]. q pre-scaled by 0.125*log2e.
// BK=64; [128][64] LDS with XOR slot swizzle via pre-swizzled global source.
__global__ __launch_bounds__(256) void k_gemm(
    const unsigned short* __restrict__ A,
    const unsigned short* __restrict__ Wb,
    const float* __restrict__ bias,
    unsigned short* __restrict__ qo,
    unsigned short* __restrict__ ko,
    unsigned short* __restrict__ vt)
{
    __shared__ unsigned short As[128*64];
    __shared__ unsigned short Bs[128*64];
    const int mt = blockIdx.x, nt = blockIdx.y;
    const int row0 = mt*128, n0 = nt*128;
    const int rloc = row0 % TSEQ;
    const int seg = (rloc < 128) ? 0 : (rloc < 2176 ? 1 : 2);
    const unsigned short* Bp = Wb + (size_t)seg * NC * DIN;
    const int tid = threadIdx.x;
    const int wid = tid >> 6, lane = tid & 63;
    const int wr = wid >> 1, wc = wid & 1;
    const int lr = lane & 15, lg = lane >> 4;
    const int rsub = lane >> 3;
    const int cgx  = (lane & 7) ^ rsub;
    f32x4 acc[4][4];
#pragma unroll
    for (int m = 0; m < 4; ++m)
#pragma unroll
        for (int n = 0; n < 4; ++n) acc[m][n] = (f32x4){0.f,0.f,0.f,0.f};

    for (int kt = 0; kt < DIN/64; ++kt){
        const int k0 = kt*64;
        __syncthreads();
#pragma unroll
        for (int i = 0; i < 4; ++i){
            const int c = wid*4 + i;
            const int r = c*8 + rsub;
            gload_lds16(&A [(size_t)(row0 + r)*DIN + k0 + cgx*8], &As[c*512]);
            gload_lds16(&Bp[(size_t)(n0  + r)*DIN + k0 + cgx*8], &Bs[c*512]);
        }
        __syncthreads();
#pragma unroll
        for (int ks = 0; ks < 2; ++ks){
            bf16x8 af[4], bfr[4];
#pragma unroll
            for (int m = 0; m < 4; ++m)
                af[m]  = *(const bf16x8*)&As[(wr*64 + m*16 + lr)*64 + (((ks*4 + lg) ^ (lr & 7))*8)];
#pragma unroll
            for (int n = 0; n < 4; ++n)
                bfr[n] = *(const bf16x8*)&Bs[(wc*64 + n*16 + lr)*64 + (((ks*4 + lg) ^ (lr & 7))*8)];
#pragma unroll
            for (int m = 0; m < 4; ++m)
#pragma unroll
                for (int n = 0; n < 4; ++n)
                    acc[m][n] = __builtin_amdgcn_mfma_f32_16x16x32_bf16(af[m], bfr[n], acc[m][n], 0, 0, 0);
        }
    }
    const int b_ = row0 / TSEQ;
    const int t0 = row0 - b_ * TSEQ;
#pragma unroll
    for (int m = 0; m < 4; ++m){
#pragma unroll
        for (int n = 0; n < 4; ++n){
            const int nglob = n0 + wc*64 + n*16 + lr;
            const float bs = bias[seg*NC + nglob];
            const int proj = nglob >> 9, hh = (nglob >> 6) & 7, e = nglob & 63;
            if (proj < 2){
                unsigned short* op = (proj == 0) ? qo : ko;
                const float scale = (proj == 0) ? 0.125f * L2E : 1.0f;
                const size_t ob = ((size_t)(b_*NH + hh) * TSEQ) * DD + e;
#pragma unroll
                for (int j = 0; j < 4; ++j){
                    const int t = t0 + wr*64 + m*16 + 4*lg + j;
                    op[ob + (size_t)t * DD] = f2bf((acc[m][n][j] + bs) * scale);
                }
            } else {
                unsigned short* vp = vt + ((size_t)(b_*NH + hh)*DD + e)*TSEQ;
                const int t = t0 + wr*64 + m*16 + 4*lg;
                u16x4 pk;
#pragma unroll
                for (int j = 0; j < 4; ++j) pk[j] = f2bf(acc[m][n][j] + bs);
                *(u16x4*)&vp[t] = pk;
            }
        }
    }
}

// Flash attention, 32x32 MFMA, fully in-register P.
// 4 waves x 32 q-rows; split-K z=3. Swapped QK^T (mfma(K,Q)) -> lane owns
// S^T[kk 32 values][q=lane&31]; C/D layout row=(r&3)+8*(r>>2)+4*(lane>>5).
// PV A-frag (P[q][kk]) built in-register: 4 cvt_pk + 2 v_permlane32_swap per
// 16-k step (no P-LDS). K/V frags: 8+8 ds_read_b128/tile-wave. LDS 32KB.
__global__ __launch_bounds__(256) void k_attn(
    const unsigned short* __restrict__ Q,
    const unsigned short* __restrict__ K,
    const unsigned short* __restrict__ Vt,
    float* __restrict__ po0,
    float* __restrict__ po1,
    float* __restrict__ out2,
    float* __restrict__ pl)
{
    __shared__ unsigned short Ks[2][64*64];
    __shared__ unsigned short Vs[2][64*64];
    const int qtb = blockIdx.x;  // 18
    const int bh  = blockIdx.y;  // 16
    const int z   = blockIdx.z;  // 3
    const int kt0 = z*12, kt1 = kt0 + 12;
    const int tid  = threadIdx.x;
    const int w    = tid >> 6;
    const int lane = tid & 63;
    const int l31  = lane & 31;
    const int h    = lane >> 5;
    const size_t qkb = (size_t)bh * TSEQ * DD;
    const size_t vtb = (size_t)bh * DD * TSEQ;
    const int q0w = qtb*128 + w*32;
    const int kd  = qtb*2 + (w >> 1);    // wave-uniform diagonal k-tile

    const int rsub = lane >> 3;
    const int cgx  = (lane & 7) ^ rsub;  // inverse swizzle on global source
    const char* Kbase  = (const char*)(K  + qkb);
    const char* Vtbase = (const char*)(Vt + vtb);

    // Q fragments (B-operand): n = q0w + l31, k-slice ds*16 + h*8
    bf16x8 aq[4];
#pragma unroll
    for (int ds = 0; ds < 4; ++ds)
        aq[ds] = *(const bf16x8*)&Q[qkb + (size_t)(q0w + l31)*DD + ds*16 + h*8];

    float lsum = 0.f;
    f32x16 o0, o1;
#pragma unroll
    for (int r = 0; r < 16; ++r){ o0[r] = 0.f; o1[r] = 0.f; }

    auto stage = [&](int kt, int b){
        const int kn = kt*64;
#pragma unroll
        for (int i = 0; i < 2; ++i){
            const int c = w*2 + i;
            const int r = c*8 + rsub;
            gload_lds16(Kbase  + (size_t)(kn + r)*128 + cgx*16,              &Ks[b][c*512]);
            gload_lds16(Vtbase + (size_t)r*(TSEQ*2) + (size_t)kn*2 + cgx*16, &Vs[b][c*512]);
        }
    };

    stage(kt0, 0);
    __syncthreads();

    const int rowA = l31 * 64;   // shorts: row base for K (kk-block0) / V (e-block0)

    int buf = 0;
    for (int kt = kt0; kt < kt1; ++kt){
        const int kc0 = kt*64;
        if (kt + 1 < kt1) stage(kt + 1, buf ^ 1);
        // QK^T: s0 = S^T[kk 0..31][q], s1 = S^T[kk 32..63][q]
        f32x16 s0, s1;
#pragma unroll
        for (int r = 0; r < 16; ++r){ s0[r] = 0.f; s1[r] = 0.f; }
#pragma unroll
        for (int ds = 0; ds < 4; ++ds){
            const int sx = (((ds*2 + h) ^ (lane & 7)) * 8);
            bf16x8 kf0 = *(const bf16x8*)&Ks[buf][rowA + sx];
            bf16x8 kf1 = *(const bf16x8*)&Ks[buf][rowA + 2048 + sx];
            s0 = __builtin_amdgcn_mfma_f32_32x32x16_bf16(kf0, aq[ds], s0, 0, 0, 0);
            s1 = __builtin_amdgcn_mfma_f32_32x32x16_bf16(kf1, aq[ds], s1, 0, 0, 0);
        }
        // softmax numerators (deferred tril bias: x e at diagonal)
        if (kt == kd){
            lsum *= EF;
#pragma unroll
            for (int r = 0; r < 16; ++r){ o0[r] *= EF; o1[r] *= EF; }
            const int qr = q0w + l31;
#pragma unroll
            for (int r = 0; r < 16; ++r){
                const int kk = kc0 + (r&3) + 8*(r>>2) + 4*h;
                const float p0 = exp2raw(s0[r] + ((kk      <= qr) ? L2E : 0.f));
                const float p1 = exp2raw(s1[r] + ((kk + 32 <= qr) ? L2E : 0.f));
                s0[r] = p0; s1[r] = p1;
                lsum += p0 + p1;
            }
        } else {
#pragma unroll
            for (int r = 0; r < 16; ++r){
                const float p0 = exp2raw(s0[r]);
                const float p1 = exp2raw(s1[r]);
                s0[r] = p0; s1[r] = p1;
                lsum += p0 + p1;
            }
        }
        // PV: per 16-k step build A-frag in-register (cvt_pk + permlane32_swap)
#pragma unroll
        for (int ks = 0; ks < 4; ++ks){
            const int rb = (ks & 1) * 8;
            unsigned int a01, a23, b01, b23;
            if (ks < 2){
                a01 = cvtpk(s0[rb+0], s0[rb+1]); a23 = cvtpk(s0[rb+2], s0[rb+3]);
                b01 = cvtpk(s0[rb+4], s0[rb+5]); b23 = cvtpk(s0[rb+6], s0[rb+7]);
            } else {
                a01 = cvtpk(s1[rb+0], s1[rb+1]); a23 = cvtpk(s1[rb+2], s1[rb+3]);
                b01 = cvtpk(s1[rb+4], s1[rb+5]); b23 = cvtpk(s1[rb+6], s1[rb+7]);
            }
            asm("v_permlane32_swap_b32 %0, %1" : "+v"(a01), "+v"(b01));
            asm("v_permlane32_swap_b32 %0, %1" : "+v"(a23), "+v"(b23));
            u32x4 fw; fw[0] = a01; fw[1] = a23; fw[2] = b01; fw[3] = b23;
            bf16x8 pa = __builtin_bit_cast(bf16x8, fw);
            const int sx = (((ks*2 + h) ^ (lane & 7)) * 8);
            bf16x8 vf0 = *(const bf16x8*)&Vs[buf][rowA + sx];
            bf16x8 vf1 = *(const bf16x8*)&Vs[buf][rowA + 2048 + sx];
            o0 = __builtin_amdgcn_mfma_f32_32x32x16_bf16(pa, vf0, o0, 0, 0, 0);
            o1 = __builtin_amdgcn_mfma_f32_32x32x16_bf16(pa, vf1, o1, 0, 0, 0);
        }
        __syncthreads();
        buf ^= 1;
    }
    if (kd >= kt1){
        lsum *= EF;
#pragma unroll
        for (int r = 0; r < 16; ++r){ o0[r] *= EF; o1[r] *= EF; }
    }
    // lane l and l+32 hold disjoint kk halves for the same q = l31
    lsum += __shfl_xor(lsum, 32);
    const int pbase = ((z*16 + bh)*18 + qtb)*128 + w*32;
    if (h == 0) pl[pbase + l31] = lsum;
    if (z < 2){
        float* po = (z == 0) ? po0 : po1;
        const size_t tb = ((size_t)(bh*18 + qtb)*128 + w*32) * 64;
#pragma unroll
        for (int r = 0; r < 16; ++r){
            const int qloc = (r&3) + 8*(r>>2) + 4*h;
            po[tb + (size_t)qloc*64 + l31]      = o0[r];
            po[tb + (size_t)qloc*64 + 32 + l31] = o1[r];
        }
    } else {
        const int b_ = bh >> 3, hh = bh & 7;
#pragma unroll
        for (int r = 0; r < 16; ++r){
            const int qloc = (r&3) + 8*(r>>2) + 4*h;
            const size_t ob = ((size_t)(b_*TSEQ + q0w + qloc))*512 + hh*64;
            out2[ob + l31]      = o0[r];
            out2[ob + 32 + l31] = o1[r];
        }
    }
}

// out = (po0 + po1 + out(po2)) / (pl0 + pl1 + pl2); po2 lives in out-layout
__global__ __launch_bounds__(256) void k_comb(
    const float* __restrict__ po0, const float* __restrict__ po1,
    const float* __restrict__ pl, float* __restrict__ out)
{
    const int qt = blockIdx.x, bh = blockIdx.y;   // 36 x 16
    const int b_ = bh >> 3, hh = bh & 7;
    const int tid = threadIdx.x;
    const int row = tid >> 2;            // 0..63
    const int c0  = (tid & 3) * 16;
    const int t128  = qt >> 1;
    const int rowin = (qt & 1)*64 + row;
    const int plb = (bh*18 + t128)*128 + rowin;
    const float inv = 1.0f / (pl[plb] + pl[(16*18*128) + plb] + pl[(2*16*18*128) + plb]);
    const size_t tb = ((size_t)(bh*18 + t128)*128 + rowin)*64 + c0;
    const size_t ob = ((size_t)(b_*TSEQ + qt*64 + row))*512 + hh*64 + c0;
#pragma unroll
    for (int i = 0; i < 4; ++i){
        f32x4 a = *(const f32x4*)&po0[tb + i*4];
        f32x4 b = *(const f32x4*)&po1[tb + i*4];
        f32x4 c = *(const f32x4*)&out[ob + i*4];
        f32x4 r;
#pragma unroll
        for (int j = 0; j < 4; ++j) r[j] = (a[j] + b[j] + c[j]) * inv;
        *(f32x4*)&out[ob + i*4] = r;
    }
}

extern "C" void kernel_launch(void* const* d_in, const int* in_sizes, int n_in,
                              void* d_out, int out_size, void* d_ws, size_t ws_size,
                              hipStream_t stream)
{
    const float* x     = (const float*)d_in[0];
    const float* ln_g  = (const float*)d_in[1];
    const float* ln_b  = (const float*)d_in[2];
    const float* ln_gs = (const float*)d_in[3];
    const float* ln_bs = (const float*)d_in[4];
    const float* ln_ge = (const float*)d_in[5];
    const float* ln_be = (const float*)d_in[6];
    const float* Wq    = (const float*)d_in[7];
    const float* Wk    = (const float*)d_in[8];
    const float* Wv    = (const float*)d_in[9];
    const float* Wq_s  = (const float*)d_in[10];
    const float* Wk_s  = (const float*)d_in[11];
    const float* Wv_s  = (const float*)d_in[12];
    const float* Wq_e  = (const float*)d_in[13];
    const float* Wk_e  = (const float*)d_in[14];
    const float* Wv_e  = (const float*)d_in[15];

    uint8_t* w = (uint8_t*)d_ws;
    unsigned short* nrm = (unsigned short*)(w);                 //  9,437,184 B
    unsigned short* wb  = (unsigned short*)(w + 9437184);       //  9,437,184 B
    float*          bia = (float*)        (w + 18874368);       //     18,432 B
    unsigned short* q_  = (unsigned short*)(w + 18892800);      //  4,718,592 B
    unsigned short* k_  = (unsigned short*)(w + 23611392);      //  4,718,592 B
    unsigned short* vt_ = (unsigned short*)(w + 28329984);      //  4,718,592 B (end 33,048,576)
    float*          pl  = (float*)        (w + 33048576);       //    442,368 B (end 33,490,944)
    float*          po0 = (float*)        (w);                  //  9,437,184 B -- reuses nrm (dead after k_gemm)
    float*          po1 = (float*)        (w + 9437184);        //  9,437,184 B -- reuses wb  (dead after k_gemm)

    WArgs wa;
    wa.W[0] = Wq_s; wa.W[1] = Wk_s; wa.W[2] = Wv_s;
    wa.W[3] = Wq;   wa.W[4] = Wk;   wa.W[5] = Wv;
    wa.W[6] = Wq_e; wa.W[7] = Wk_e; wa.W[8] = Wv_e;
    wa.g[0] = ln_gs; wa.g[1] = ln_g; wa.g[2] = ln_ge;
    wa.bv[0] = ln_bs; wa.bv[1] = ln_b; wa.bv[2] = ln_be;

    float* out = (float*)d_out;
    k_pre <<<dim3(5832),      dim3(256), 0, stream>>>(wa, x, wb, bia, nrm);
    k_gemm<<<dim3(36, 12),    dim3(256), 0, stream>>>(nrm, wb, bia, q_, k_, vt_);
    k_attn<<<dim3(18, 16, 3), dim3(256), 0, stream>>>(q_, k_, vt_, po0, po1, out, pl);
    k_comb<<<dim3(36, 16),    dim3(256), 0, stream>>>(po0, po1, pl, out);
}